// Round 1
// baseline (747.994 us; speedup 1.0000x reference)
//
#include <hip/hip_runtime.h>

// GraphAttentionLayer on MI355X (gfx950)
// N=8192, IN_F=128, N_HID=64, OUT_F=128
//
// Kernel 1 (proj): Whs=h@Ws, Wht=h@Wt, Whc=h@Wc (fp32 VALU, trivial FLOPs).
//   Whs/Wht stored as bf16 hi+lo split (for near-fp32 MFMA scores).
//   Whc stored transposed (WhcT[128][N] bf16) so PV B-fragments are
//   row-contiguous per lane.
// Kernel 2 (attn): flash-style fused masked-softmax attention.
//   grid 256 blocks x 512 thr (8 waves: 2 row-groups x 4 col-groups),
//   BR=32 rows/block, CT=128 cols/tile, mfma_f32_16x16x32_bf16.
//   Scores: e = hi*hi + hi*lo + lo*hi (3 MFMAs, drops lo*lo ~1e-6 rel).
//   Masked score = -9e15f exactly (matches reference semantics incl.
//   all-masked-row uniform fallback, no special cases).
//   P goes C-layout -> LDS (bf16) -> A-layout for PV (m120 pattern).

#define NN 8192
#define INF_ 128
#define NHID 64
#define OUTF 128
#define NEGC -9.0e15f

typedef unsigned short u16;
typedef __attribute__((ext_vector_type(8))) short bf16x8;
typedef __attribute__((ext_vector_type(4))) float f32x4;

static __device__ __forceinline__ u16 f2bf(float x) {
  union { float f; unsigned u; } v; v.f = x;
  unsigned lsb = (v.u >> 16) & 1u;
  v.u += 0x7fffu + lsb;            // round-to-nearest-even
  return (u16)(v.u >> 16);
}
static __device__ __forceinline__ float bf2f(u16 h) {
  union { float f; unsigned u; } v; v.u = ((unsigned)h) << 16;
  return v.f;
}
static __device__ __forceinline__ f32x4 mfma16(bf16x8 a, bf16x8 b, f32x4 c) {
  return __builtin_amdgcn_mfma_f32_16x16x32_bf16(a, b, c, 0, 0, 0);
}

// ---------------------------------------------------------------- kernel 1
__global__ __launch_bounds__(256) void proj_kernel(
    const float* __restrict__ h, const float* __restrict__ Ws,
    const float* __restrict__ Wt, const float* __restrict__ Wc,
    u16* __restrict__ whs_hi, u16* __restrict__ whs_lo,
    u16* __restrict__ wht_hi, u16* __restrict__ wht_lo,
    u16* __restrict__ whcT) {
  __shared__ float hbuf[8][INF_];
  const int tid = threadIdx.x;
  const int r0 = blockIdx.x * 8;
  for (int i = tid; i < 8 * INF_; i += 256)
    hbuf[i >> 7][i & 127] = h[r0 * INF_ + i];
  __syncthreads();

  float acc[8];
#pragma unroll
  for (int r = 0; r < 8; ++r) acc[r] = 0.f;

  if (tid < 128) {
    // threads 0..63: Ws col tid ; 64..127: Wt col tid-64  (both ld=64)
    const float* W = (tid < 64) ? (Ws + tid) : (Wt + (tid - 64));
#pragma unroll 8
    for (int k = 0; k < INF_; ++k) {
      float w = W[k * NHID];
#pragma unroll
      for (int r = 0; r < 8; ++r) acc[r] += hbuf[r][k] * w;
    }
    const int col = tid & 63;
    u16* hi = (tid < 64) ? whs_hi : wht_hi;
    u16* lo = (tid < 64) ? whs_lo : wht_lo;
#pragma unroll
    for (int r = 0; r < 8; ++r) {
      float v = acc[r];
      u16 hb = f2bf(v);
      hi[(size_t)(r0 + r) * NHID + col] = hb;
      lo[(size_t)(r0 + r) * NHID + col] = f2bf(v - bf2f(hb));
    }
  } else {
    const int col = tid - 128;  // 0..127, Wc column (ld=128)
    const float* W = Wc + col;
#pragma unroll 8
    for (int k = 0; k < INF_; ++k) {
      float w = W[k * OUTF];
#pragma unroll
      for (int r = 0; r < 8; ++r) acc[r] += hbuf[r][k] * w;
    }
    union { u16 s[8]; uint4 v; } pk;
#pragma unroll
    for (int r = 0; r < 8; ++r) pk.s[r] = f2bf(acc[r]);
    // WhcT[col][r0..r0+7] — 16B packed store, 16B aligned (r0 % 8 == 0)
    *reinterpret_cast<uint4*>(whcT + (size_t)col * NN + r0) = pk.v;
  }
}

// ---------------------------------------------------------------- kernel 2
__global__ __launch_bounds__(512, 2) void attn_kernel(
    const u16* __restrict__ whs_hi, const u16* __restrict__ whs_lo,
    const u16* __restrict__ wht_hi, const u16* __restrict__ wht_lo,
    const u16* __restrict__ whcT, const int* __restrict__ adj,
    float* __restrict__ out) {
  // LDS: P (bf16, padded stride 136 for b128-aligned A-frag reads) + softmax state
  __shared__ __align__(16) u16 Pbuf[32][136];
  __shared__ float redmax[2][4][16];
  __shared__ float redsum[2][4][16];
  __shared__ float m_st[32];
  __shared__ float l_st[32];

  const int tid = threadIdx.x;
  const int w = tid >> 6;       // wave 0..7
  const int lane = tid & 63;
  const int q = lane >> 4;      // quad 0..3
  const int ln = lane & 15;
  const int wr = w & 1;         // row-group: rows 16*wr .. +15 (local)
  const int wc = w >> 2 == 0 ? (w >> 1) : (w >> 1);  // col-group 0..3
  const int row0 = blockIdx.x * 32;

  if (tid < 32) { m_st[tid] = -__builtin_inff(); l_st[tid] = 0.f; }

  // Loop-invariant A-fragments: Whs rows row0+16*wr+ln, k = kh*32 + q*8 + j
  const int arow = row0 + 16 * wr + ln;
  bf16x8 a_hi[2], a_lo[2];
#pragma unroll
  for (int kh = 0; kh < 2; ++kh) {
    a_hi[kh] = *reinterpret_cast<const bf16x8*>(
        whs_hi + (size_t)arow * NHID + kh * 32 + q * 8);
    a_lo[kh] = *reinterpret_cast<const bf16x8*>(
        whs_lo + (size_t)arow * NHID + kh * 32 + q * 8);
  }

  f32x4 oacc[2];
#pragma unroll
  for (int t = 0; t < 2; ++t)
#pragma unroll
    for (int g = 0; g < 4; ++g) oacc[t][g] = 0.f;

  __syncthreads();  // m_st / l_st init visible

  for (int jt = 0; jt < NN / 128; ++jt) {
    const int j0 = jt * 128;

    // ---- scores S[32 x 128]; this wave: rows 16*wr.., cols 32*wc..+31
    float s[2][4];
#pragma unroll
    for (int t = 0; t < 2; ++t) {
      const int bcol = j0 + 32 * wc + 16 * t + ln;  // global column (B n=ln)
      const u16* bh = wht_hi + (size_t)bcol * NHID + q * 8;
      const u16* bl = wht_lo + (size_t)bcol * NHID + q * 8;
      bf16x8 bh0 = *reinterpret_cast<const bf16x8*>(bh);
      bf16x8 bh1 = *reinterpret_cast<const bf16x8*>(bh + 32);
      bf16x8 bl0 = *reinterpret_cast<const bf16x8*>(bl);
      bf16x8 bl1 = *reinterpret_cast<const bf16x8*>(bl + 32);
      f32x4 sa;
#pragma unroll
      for (int g = 0; g < 4; ++g) sa[g] = 0.f;
      sa = mfma16(a_lo[0], bh0, sa);   // lo*hi
      sa = mfma16(a_hi[0], bl0, sa);   // hi*lo
      sa = mfma16(a_hi[0], bh0, sa);   // hi*hi
      sa = mfma16(a_lo[1], bh1, sa);
      sa = mfma16(a_hi[1], bl1, sa);
      sa = mfma16(a_hi[1], bh1, sa);
      // mask: C/D layout row = q*4+g, col = ln
#pragma unroll
      for (int g = 0; g < 4; ++g) {
        int r = row0 + 16 * wr + q * 4 + g;
        int c = j0 + 32 * wc + 16 * t + ln;
        s[t][g] = (adj[r * NN + c] > 0) ? sa[g] : NEGC;
      }
    }

    // ---- wave-local row max over its 32 cols (reduce across 16 ln-lanes)
    float mr[4];
#pragma unroll
    for (int g = 0; g < 4; ++g) mr[g] = fmaxf(s[0][g], s[1][g]);
#pragma unroll
    for (int msk = 1; msk <= 8; msk <<= 1)
#pragma unroll
      for (int g = 0; g < 4; ++g) mr[g] = fmaxf(mr[g], __shfl_xor(mr[g], msk));
    if (ln == 0)
#pragma unroll
      for (int g = 0; g < 4; ++g) redmax[wr][wc][q * 4 + g] = mr[g];

    __syncthreads();  // barrier C: redmax ready; prev-iter Pbuf reads done

    float mnew[4], alpha[4], srow[4];
#pragma unroll
    for (int g = 0; g < 4; ++g) {
      int rr = q * 4 + g;
      float tm = fmaxf(fmaxf(redmax[wr][0][rr], redmax[wr][1][rr]),
                       fmaxf(redmax[wr][2][rr], redmax[wr][3][rr]));
      float mo = m_st[16 * wr + rr];
      float mn = fmaxf(mo, tm);
      mnew[g] = mn;
      alpha[g] = __expf(mo - mn);   // -inf start -> alpha 0; NEG-NEG -> 1
      srow[g] = 0.f;
    }
#pragma unroll
    for (int t = 0; t < 2; ++t)
#pragma unroll
      for (int g = 0; g < 4; ++g) {
        float p = __expf(s[t][g] - mnew[g]);
        srow[g] += p;
        Pbuf[16 * wr + q * 4 + g][32 * wc + 16 * t + ln] = f2bf(p);
      }
#pragma unroll
    for (int msk = 1; msk <= 8; msk <<= 1)
#pragma unroll
      for (int g = 0; g < 4; ++g) srow[g] += __shfl_xor(srow[g], msk);
    if (ln == 0)
#pragma unroll
      for (int g = 0; g < 4; ++g) redsum[wr][wc][q * 4 + g] = srow[g];

    // rescale O accumulators (same row mapping q*4+g as S)
#pragma unroll
    for (int t = 0; t < 2; ++t)
#pragma unroll
      for (int g = 0; g < 4; ++g) oacc[t][g] *= alpha[g];

    __syncthreads();  // barrier E: Pbuf + redsum ready

    // m/l state update by wc==0 waves only
    if (wc == 0 && ln == 0) {
#pragma unroll
      for (int g = 0; g < 4; ++g) {
        int rr = q * 4 + g;
        float ts = redsum[wr][0][rr] + redsum[wr][1][rr] +
                   redsum[wr][2][rr] + redsum[wr][3][rr];
        l_st[16 * wr + rr] = l_st[16 * wr + rr] * alpha[g] + ts;
        m_st[16 * wr + rr] = mnew[g];
      }
    }

    // ---- PV: O[32 x 128] += P[32 x 128] @ Whc[j0..j0+127][128]
    // this wave: rows 16*wr.., out cols 32*wc..+31 (2 tiles of 16)
#pragma unroll
    for (int kh = 0; kh < 4; ++kh) {
      bf16x8 pa = *reinterpret_cast<const bf16x8*>(
          &Pbuf[16 * wr + ln][kh * 32 + q * 8]);  // A: m=ln, k contiguous
#pragma unroll
      for (int t = 0; t < 2; ++t) {
        const int ocol = 32 * wc + 16 * t + ln;   // B: n=ln
        bf16x8 wb = *reinterpret_cast<const bf16x8*>(
            whcT + (size_t)ocol * NN + j0 + kh * 32 + q * 8);
        oacc[t] = mfma16(pa, wb, oacc[t]);
      }
    }
  }

  __syncthreads();  // final l_st visible
  float li[4];
#pragma unroll
  for (int g = 0; g < 4; ++g) li[g] = 1.0f / l_st[16 * wr + q * 4 + g];
#pragma unroll
  for (int t = 0; t < 2; ++t)
#pragma unroll
    for (int g = 0; g < 4; ++g) {
      int r = row0 + 16 * wr + q * 4 + g;
      int c = 32 * wc + 16 * t + ln;
      out[(size_t)r * OUTF + c] = oacc[t][g] * li[g];
    }
}

// ---------------------------------------------------------------- launch
extern "C" void kernel_launch(void* const* d_in, const int* in_sizes, int n_in,
                              void* d_out, int out_size, void* d_ws, size_t ws_size,
                              hipStream_t stream) {
  const float* h  = (const float*)d_in[0];
  const int*   adj = (const int*)d_in[1];
  const float* Ws = (const float*)d_in[2];
  const float* Wt = (const float*)d_in[3];
  const float* Wc = (const float*)d_in[4];
  float* out = (float*)d_out;

  char* ws = (char*)d_ws;
  // ws layout (6 MB total): whs_hi | whs_lo | wht_hi | wht_lo  (1 MB each)
  //                         | whcT (2 MB)
  u16* whs_hi = (u16*)(ws);
  u16* whs_lo = (u16*)(ws + (size_t)NN * NHID * 2);
  u16* wht_hi = (u16*)(ws + (size_t)NN * NHID * 4);
  u16* wht_lo = (u16*)(ws + (size_t)NN * NHID * 6);
  u16* whcT   = (u16*)(ws + (size_t)NN * NHID * 8);

  proj_kernel<<<NN / 8, 256, 0, stream>>>(h, Ws, Wt, Wc, whs_hi, whs_lo,
                                          wht_hi, wht_lo, whcT);
  attn_kernel<<<NN / 32, 512, 0, stream>>>(whs_hi, whs_lo, wht_hi, wht_lo,
                                           whcT, adj, out);
}

// Round 2
// 608.145 us; speedup vs baseline: 1.2300x; 1.2300x over previous
//
#include <hip/hip_runtime.h>

// GraphAttentionLayer on MI355X (gfx950)
// N=8192, IN_F=128, N_HID=64, OUT_F=128
//
// R2 redesign: barrier-free flash attention with split-K.
//  - proj: Whs/Wht (bf16 hi+lo split), WhcT (bf16, transposed). Unchanged.
//  - attn: each WAVE independently owns 16 rows x full 128-col j-tiles.
//    Softmax stats (m,l) in registers, reduced via intra-wave shfl_xor.
//    P transpose (C-layout -> A-layout) via WAVE-PRIVATE LDS slab: no
//    __syncthreads anywhere in the K-loop (wave-synchronous lgkmcnt only).
//    Columns split into C chunks (flash split-K) -> 512*C independent
//    waves -> 16 waves/CU at C=8 (vs 8 coupled waves R1). Partial O/m/l
//    to ws; combine kernel merges. C picked from ws_size; C==1 writes
//    d_out directly (6 MB ws, the R1-proven footprint).
//  - adj read via nontemporal loads (single-use 256 MB stream; keep
//    wht/whcT L2-resident).

#define NN 8192
#define INF_ 128
#define NHID 64
#define OUTF 128
#define NEGC -9.0e15f

typedef unsigned short u16;
typedef __attribute__((ext_vector_type(8))) short bf16x8;
typedef __attribute__((ext_vector_type(4))) float f32x4;

static __device__ __forceinline__ u16 f2bf(float x) {
  union { float f; unsigned u; } v; v.f = x;
  unsigned lsb = (v.u >> 16) & 1u;
  v.u += 0x7fffu + lsb;            // round-to-nearest-even
  return (u16)(v.u >> 16);
}
static __device__ __forceinline__ float bf2f(u16 h) {
  union { float f; unsigned u; } v; v.u = ((unsigned)h) << 16;
  return v.f;
}
static __device__ __forceinline__ f32x4 mfma16(bf16x8 a, bf16x8 b, f32x4 c) {
  return __builtin_amdgcn_mfma_f32_16x16x32_bf16(a, b, c, 0, 0, 0);
}

// ---------------------------------------------------------------- kernel 1
__global__ __launch_bounds__(256) void proj_kernel(
    const float* __restrict__ h, const float* __restrict__ Ws,
    const float* __restrict__ Wt, const float* __restrict__ Wc,
    u16* __restrict__ whs_hi, u16* __restrict__ whs_lo,
    u16* __restrict__ wht_hi, u16* __restrict__ wht_lo,
    u16* __restrict__ whcT) {
  __shared__ float hbuf[8][INF_];
  const int tid = threadIdx.x;
  const int r0 = blockIdx.x * 8;
  for (int i = tid; i < 8 * INF_; i += 256)
    hbuf[i >> 7][i & 127] = h[r0 * INF_ + i];
  __syncthreads();

  float acc[8];
#pragma unroll
  for (int r = 0; r < 8; ++r) acc[r] = 0.f;

  if (tid < 128) {
    const float* W = (tid < 64) ? (Ws + tid) : (Wt + (tid - 64));
#pragma unroll 8
    for (int k = 0; k < INF_; ++k) {
      float w = W[k * NHID];
#pragma unroll
      for (int r = 0; r < 8; ++r) acc[r] += hbuf[r][k] * w;
    }
    const int col = tid & 63;
    u16* hi = (tid < 64) ? whs_hi : wht_hi;
    u16* lo = (tid < 64) ? whs_lo : wht_lo;
#pragma unroll
    for (int r = 0; r < 8; ++r) {
      float v = acc[r];
      u16 hb = f2bf(v);
      hi[(size_t)(r0 + r) * NHID + col] = hb;
      lo[(size_t)(r0 + r) * NHID + col] = f2bf(v - bf2f(hb));
    }
  } else {
    const int col = tid - 128;
    const float* W = Wc + col;
#pragma unroll 8
    for (int k = 0; k < INF_; ++k) {
      float w = W[k * OUTF];
#pragma unroll
      for (int r = 0; r < 8; ++r) acc[r] += hbuf[r][k] * w;
    }
    union { u16 s[8]; uint4 v; } pk;
#pragma unroll
    for (int r = 0; r < 8; ++r) pk.s[r] = f2bf(acc[r]);
    *reinterpret_cast<uint4*>(whcT + (size_t)col * NN + r0) = pk.v;
  }
}

// ---------------------------------------------------------------- kernel 2
// Wave-independent flash attention. Block = 4 waves (disjoint work).
// Wave gw = blockIdx*4 + w: row-group rg = gw & 511 (rows rg*16..+15),
// column chunk = gw >> 9 (j in [chunk*iters*128, ...)).
__global__ __launch_bounds__(256) void attn_kernel(
    const u16* __restrict__ whs_hi, const u16* __restrict__ whs_lo,
    const u16* __restrict__ wht_hi, const u16* __restrict__ wht_lo,
    const u16* __restrict__ whcT, const int* __restrict__ adj,
    float* __restrict__ Opart, float* __restrict__ mpart,
    float* __restrict__ lpart, float* __restrict__ out,
    int iters, int final_write) {
  // wave-private P slabs: stride 136 u16 -> q-groups hit disjoint bank
  // octets on writes, <=2-way (free) on b128 reads.
  __shared__ __align__(16) u16 Pbuf[4][16][136];

  const int tid = threadIdx.x;
  const int w = tid >> 6;
  const int lane = tid & 63;
  const int q = lane >> 4;
  const int ln = lane & 15;
  const int gw = blockIdx.x * 4 + w;
  const int rg = gw & 511;
  const int chunk = gw >> 9;
  const int row0 = rg * 16;

  // Loop-invariant A-fragments: Whs rows row0+ln, k = kh*32 + q*8 + j
  bf16x8 a_hi[2], a_lo[2];
#pragma unroll
  for (int kh = 0; kh < 2; ++kh) {
    a_hi[kh] = *reinterpret_cast<const bf16x8*>(
        whs_hi + (size_t)(row0 + ln) * NHID + kh * 32 + q * 8);
    a_lo[kh] = *reinterpret_cast<const bf16x8*>(
        whs_lo + (size_t)(row0 + ln) * NHID + kh * 32 + q * 8);
  }

  f32x4 oacc[8];
#pragma unroll
  for (int ot = 0; ot < 8; ++ot)
#pragma unroll
    for (int g = 0; g < 4; ++g) oacc[ot][g] = 0.f;

  float m_old[4], l_run[4];
#pragma unroll
  for (int g = 0; g < 4; ++g) { m_old[g] = -__builtin_inff(); l_run[g] = 0.f; }

  for (int jt = 0; jt < iters; ++jt) {
    const int j0 = (chunk * iters + jt) * 128;

    // ---- scores S[16 x 128] for this wave (8 n-tiles), hi/lo split
    float s[8][4];
#pragma unroll
    for (int nt = 0; nt < 8; ++nt) {
      const int bcol = j0 + nt * 16 + ln;
      const u16* bh = wht_hi + (size_t)bcol * NHID + q * 8;
      const u16* bl = wht_lo + (size_t)bcol * NHID + q * 8;
      bf16x8 bh0 = *reinterpret_cast<const bf16x8*>(bh);
      bf16x8 bh1 = *reinterpret_cast<const bf16x8*>(bh + 32);
      bf16x8 bl0 = *reinterpret_cast<const bf16x8*>(bl);
      bf16x8 bl1 = *reinterpret_cast<const bf16x8*>(bl + 32);
      f32x4 sa;
#pragma unroll
      for (int g = 0; g < 4; ++g) sa[g] = 0.f;
      sa = mfma16(a_lo[0], bh0, sa);   // lo*hi
      sa = mfma16(a_hi[0], bl0, sa);   // hi*lo
      sa = mfma16(a_hi[0], bh0, sa);   // hi*hi
      sa = mfma16(a_lo[1], bh1, sa);
      sa = mfma16(a_hi[1], bl1, sa);
      sa = mfma16(a_hi[1], bh1, sa);
      // mask (C/D layout: row = q*4+g, col = ln). adj is a single-use
      // 256MB stream -> nontemporal.
#pragma unroll
      for (int g = 0; g < 4; ++g) {
        const int r = row0 + q * 4 + g;
        int av = __builtin_nontemporal_load(adj + (size_t)r * NN + bcol);
        s[nt][g] = (av > 0) ? sa[g] : NEGC;
      }
    }

    // ---- in-wave online softmax (rows q*4+g live in 16-lane ln-groups)
    float mr[4];
#pragma unroll
    for (int g = 0; g < 4; ++g) mr[g] = s[0][g];
#pragma unroll
    for (int nt = 1; nt < 8; ++nt)
#pragma unroll
      for (int g = 0; g < 4; ++g) mr[g] = fmaxf(mr[g], s[nt][g]);
#pragma unroll
    for (int msk = 1; msk <= 8; msk <<= 1)
#pragma unroll
      for (int g = 0; g < 4; ++g) mr[g] = fmaxf(mr[g], __shfl_xor(mr[g], msk));

    float mn[4], alpha[4], ps[4];
#pragma unroll
    for (int g = 0; g < 4; ++g) {
      mn[g] = fmaxf(m_old[g], mr[g]);
      alpha[g] = __expf(m_old[g] - mn[g]);  // -inf start -> 0
      m_old[g] = mn[g];
      ps[g] = 0.f;
    }
#pragma unroll
    for (int nt = 0; nt < 8; ++nt)
#pragma unroll
      for (int g = 0; g < 4; ++g) {
        float p = __expf(s[nt][g] - mn[g]);
        ps[g] += p;
        Pbuf[w][q * 4 + g][nt * 16 + ln] = f2bf(p);
      }
#pragma unroll
    for (int msk = 1; msk <= 8; msk <<= 1)
#pragma unroll
      for (int g = 0; g < 4; ++g) ps[g] += __shfl_xor(ps[g], msk);
#pragma unroll
    for (int g = 0; g < 4; ++g) l_run[g] = l_run[g] * alpha[g] + ps[g];
#pragma unroll
    for (int ot = 0; ot < 8; ++ot)
#pragma unroll
      for (int g = 0; g < 4; ++g) oacc[ot][g] *= alpha[g];

    // ---- PV: O[16x128] += P @ WhcT^T  (wave-private LDS transpose;
    // no barrier: same-wave ds ordering via lgkmcnt only)
#pragma unroll
    for (int kh = 0; kh < 4; ++kh) {
      bf16x8 pa = *reinterpret_cast<const bf16x8*>(
          &Pbuf[w][ln][kh * 32 + q * 8]);   // A: m=ln, k contiguous
#pragma unroll
      for (int ot = 0; ot < 8; ++ot) {
        bf16x8 wb = *reinterpret_cast<const bf16x8*>(
            whcT + (size_t)(ot * 16 + ln) * NN + j0 + kh * 32 + q * 8);
        oacc[ot] = mfma16(pa, wb, oacc[ot]);
      }
    }
  }

  // ---- epilogue
  if (final_write) {
#pragma unroll
    for (int ot = 0; ot < 8; ++ot)
#pragma unroll
      for (int g = 0; g < 4; ++g) {
        const int r = row0 + q * 4 + g;
        out[(size_t)r * OUTF + ot * 16 + ln] = oacc[ot][g] / l_run[g];
      }
  } else {
#pragma unroll
    for (int ot = 0; ot < 8; ++ot)
#pragma unroll
      for (int g = 0; g < 4; ++g) {
        const int r = row0 + q * 4 + g;
        Opart[((size_t)chunk * NN + r) * OUTF + ot * 16 + ln] = oacc[ot][g];
      }
    if (ln == 0) {
#pragma unroll
      for (int g = 0; g < 4; ++g) {
        const int r = row0 + q * 4 + g;
        mpart[chunk * NN + r] = m_old[g];
        lpart[chunk * NN + r] = l_run[g];
      }
    }
  }
}

// ---------------------------------------------------------------- kernel 3
__global__ __launch_bounds__(256) void combine_kernel(
    const float* __restrict__ Opart, const float* __restrict__ mpart,
    const float* __restrict__ lpart, float* __restrict__ out, int C) {
  const int idx = blockIdx.x * 256 + threadIdx.x;  // over N*OUTF
  const int row = idx >> 7;
  float M = -__builtin_inff();
  for (int c = 0; c < C; ++c) M = fmaxf(M, mpart[c * NN + row]);
  float den = 0.f, num = 0.f;
  for (int c = 0; c < C; ++c) {
    float wgt = __expf(mpart[c * NN + row] - M);
    den += lpart[c * NN + row] * wgt;
    num += Opart[(size_t)c * NN * OUTF + idx] * wgt;
  }
  out[idx] = num / den;
}

// ---------------------------------------------------------------- launch
extern "C" void kernel_launch(void* const* d_in, const int* in_sizes, int n_in,
                              void* d_out, int out_size, void* d_ws, size_t ws_size,
                              hipStream_t stream) {
  const float* h   = (const float*)d_in[0];
  const int*   adj = (const int*)d_in[1];
  const float* Ws  = (const float*)d_in[2];
  const float* Wt  = (const float*)d_in[3];
  const float* Wc  = (const float*)d_in[4];
  float* out = (float*)d_out;

  char* ws = (char*)d_ws;
  const size_t MB = 1024 * 1024;
  // ws layout: whs_hi|whs_lo|wht_hi|wht_lo (1MB each) | whcT (2MB)
  //            | mpart (256KB) | lpart (256KB) | Opart (C*4MB)
  u16* whs_hi = (u16*)(ws);
  u16* whs_lo = (u16*)(ws + 1 * MB);
  u16* wht_hi = (u16*)(ws + 2 * MB);
  u16* wht_lo = (u16*)(ws + 3 * MB);
  u16* whcT   = (u16*)(ws + 4 * MB);
  float* mpart = (float*)(ws + 6 * MB);
  float* lpart = (float*)(ws + 6 * MB + 256 * 1024);
  float* Opart = (float*)(ws + 6 * MB + 512 * 1024);

  // pick largest split C in {8,4,2} that fits ws; else C=1 direct-write
  // (needs only the 6MB footprint proven in R1).
  int C = 8;
  while (C > 1 &&
         6 * MB + 512 * 1024 + (size_t)C * NN * OUTF * sizeof(float) > ws_size)
    C >>= 1;
  const int final_write = (C == 1) ? 1 : 0;
  const int iters = 64 / C;

  proj_kernel<<<NN / 8, 256, 0, stream>>>(h, Ws, Wt, Wc, whs_hi, whs_lo,
                                          wht_hi, wht_lo, whcT);
  attn_kernel<<<128 * C, 256, 0, stream>>>(whs_hi, whs_lo, wht_hi, wht_lo,
                                           whcT, adj, Opart, mpart, lpart,
                                           out, iters, final_write);
  if (!final_write)
    combine_kernel<<<NN * OUTF / 256, 256, 0, stream>>>(Opart, mpart, lpart,
                                                        out, C);
}